// Round 2
// baseline (1708.416 us; speedup 1.0000x reference)
//
#include <hip/hip_runtime.h>

#define T_TOK 16384
#define HDIM  1024
#define IDIM  2048
#define NEXP  8
#define CNT_STRIDE 32     // pad each expert counter to its own 128B cache line
#define TOK_PER_BLK 32    // tokens handled per 256-thread router block

typedef __attribute__((ext_vector_type(8))) short bf16x8;
typedef __attribute__((ext_vector_type(4))) float f32x4;
typedef unsigned short u16;
typedef unsigned int u32;

typedef __attribute__((address_space(1))) const unsigned int gas_u32;
typedef __attribute__((address_space(3))) unsigned int las_u32;

// async global->LDS, 16B per lane; LDS dest = base + lane*16 (wave-uniform base)
__device__ __forceinline__ void gl16(const void* g, void* l) {
  __builtin_amdgcn_global_load_lds((gas_u32*)g, (las_u32*)l, 16, 0, 0);
}

__device__ __forceinline__ u16 f2bf(float f) {
  union { float f; u32 i; } v; v.f = f;
  u32 r = v.i + 0x7FFF + ((v.i >> 16) & 1);  // RNE
  return (u16)(r >> 16);
}
__device__ __forceinline__ u32 pack2(float a, float b) {
  return (u32)f2bf(a) | ((u32)f2bf(b) << 16);
}

// ---------------- f32 -> bf16 elementwise convert ---------------------------
__global__ __launch_bounds__(256) void cvt_kernel(
    const float* __restrict__ s, u16* __restrict__ d, int n)
{
  int i = (blockIdx.x * 256 + threadIdx.x) * 4;
  if (i < n) {
    f32x4 v = *(const f32x4*)(s + i);
    uint2 o; o.x = pack2(v[0], v[1]); o.y = pack2(v[2], v[3]);
    *(uint2*)(d + i) = o;
  }
}

__global__ void init_counts(int* counts) {
  counts[threadIdx.x] = 0;  // launched with NEXP*CNT_STRIDE threads
}

// ---------------- router: f64 logits, top2 on logits ------------------------
// block-aggregated list append (ballot+popc, 1 atomic per block*expert,
// padded counters) to kill same-cache-line atomic serialization.
__global__ __launch_bounds__(256) void router_kernel(
    const float* __restrict__ x, const float* __restrict__ Wr,
    const float* __restrict__ rb, float* __restrict__ cw,
    int* __restrict__ counts, int* __restrict__ lists)
{
  __shared__ __align__(16) float sWr[NEXP * HDIM];   // 32 KB
  __shared__ int pickE[2 * TOK_PER_BLK];             // 64 slots
  __shared__ int pickT[2 * TOK_PER_BLK];

  const int tid = threadIdx.x;
  const int lane = tid & 63;
  const int wv = tid >> 6;

  for (int i = tid; i < NEXP * HDIM / 4; i += 256)
    ((f32x4*)sWr)[i] = ((const f32x4*)Wr)[i];

  float rbl[NEXP];
  #pragma unroll
  for (int e = 0; e < NEXP; ++e) rbl[e] = rb[e];

  __syncthreads();

  const int t_base = blockIdx.x * TOK_PER_BLK + wv * (TOK_PER_BLK / 4);
  for (int j = 0; j < TOK_PER_BLK / 4; ++j) {
    const int t = t_base + j;
    const float* xrow = x + (size_t)t * HDIM;
    f32x4 xv[4];
    #pragma unroll
    for (int c = 0; c < 4; ++c) xv[c] = *(const f32x4*)(xrow + c * 256 + lane * 4);

    double acc[NEXP];
    #pragma unroll
    for (int e = 0; e < NEXP; ++e) {
      const float* wr = sWr + e * HDIM;
      double a = 0.0;
      #pragma unroll
      for (int c = 0; c < 4; ++c) {
        f32x4 w4 = *(const f32x4*)(wr + c * 256 + lane * 4);
        a += (double)xv[c][0] * (double)w4[0];
        a += (double)xv[c][1] * (double)w4[1];
        a += (double)xv[c][2] * (double)w4[2];
        a += (double)xv[c][3] * (double)w4[3];
      }
      acc[e] = a;
    }
    // stage 1: butterfly reduce within octets (lane bits 0..2)
    #pragma unroll
    for (int e = 0; e < NEXP; ++e) {
      double a = acc[e];
      a += __shfl_xor(a, 1, 64);
      a += __shfl_xor(a, 2, 64);
      a += __shfl_xor(a, 4, 64);
      acc[e] = a;
    }
    // stage 2: lane selects expert (lane&7) — static-index cndmask tree
    double s0 = (lane & 1) ? acc[1] : acc[0];
    double s1 = (lane & 1) ? acc[3] : acc[2];
    double s2 = (lane & 1) ? acc[5] : acc[4];
    double s3 = (lane & 1) ? acc[7] : acc[6];
    double u0 = (lane & 2) ? s1 : s0;
    double u1 = (lane & 2) ? s3 : s2;
    double v  = (lane & 4) ? u1 : u0;
    // stage 3: reduce across octets (lane bits 3..5)
    v += __shfl_xor(v, 8, 64);
    v += __shfl_xor(v, 16, 64);
    v += __shfl_xor(v, 32, 64);
    // broadcast all 8 logits to all lanes
    double l[NEXP];
    #pragma unroll
    for (int e = 0; e < NEXP; ++e) l[e] = __shfl(v, e, 64) + (double)rbl[e];

    if (lane == 0) {
      // top-2 on logits (sigmoid monotone); strict > = first-max on tie
      int i1 = 0;
      #pragma unroll
      for (int e = 1; e < NEXP; ++e) if (l[e] > l[i1]) i1 = e;
      int i2 = -1;
      #pragma unroll
      for (int e = 0; e < NEXP; ++e) {
        if (e == i1) continue;
        if (i2 < 0 || l[e] > l[i2]) i2 = e;
      }
      float p1 = (float)(1.0 / (1.0 + exp(-l[i1])));
      float p2 = (float)(1.0 / (1.0 + exp(-l[i2])));
      cw[(size_t)t * NEXP + i1] = p1;
      cw[(size_t)t * NEXP + i2] = p2;
      int slot = (wv * (TOK_PER_BLK / 4) + j) * 2;
      pickE[slot] = i1; pickE[slot + 1] = i2;
      pickT[slot] = t;  pickT[slot + 1] = t;
    }
  }
  __syncthreads();

  // phase 2: block-aggregated append; wave wv handles experts {wv, wv+4}
  const int myE = pickE[lane];
  const int myT = pickT[lane];
  #pragma unroll
  for (int ei = 0; ei < 2; ++ei) {
    int e = wv + ei * 4;
    unsigned long long b = __ballot(myE == e);
    int cnt = __popcll(b);
    int base = 0;
    if (lane == 0) base = atomicAdd(&counts[e * CNT_STRIDE], cnt);
    base = __shfl(base, 0, 64);
    if (myE == e)
      lists[(size_t)e * T_TOK + base + __popcll(b & ((1ull << lane) - 1))] = myT;
  }
}

// ---------------- pass A: h = silu(Xg Wg^T) * (Xg Wu^T) ---------------------
// SRC==0: x/W pre-converted bf16 -> global_load_lds direct staging (m97 pattern)
// SRC==1: stage from f32 with inline cvt (fallback).
template<int SRC>
__global__ __launch_bounds__(256, 2) void moe_gateup_k(
    const u16* __restrict__ xb, const float* __restrict__ xf,
    const u16* __restrict__ Wg_b, const u16* __restrict__ Wu_b,
    const float* __restrict__ Wg_f, const float* __restrict__ Wu_f,
    const int* __restrict__ list, const int* __restrict__ count_ptr,
    u16* __restrict__ hbuf, int c0)
{
  __shared__ __align__(16) u16 sA[128 * 32];
  __shared__ __align__(16) u16 sG[128 * 32];
  __shared__ __align__(16) u16 sU[128 * 32];

  const int cnt = count_ptr ? *count_ptr : T_TOK;
  const int remain = cnt - c0;
  const int m0 = blockIdx.y * 128;
  if (m0 >= remain) return;
  const int n0 = blockIdx.x * 128;

  const int tid = threadIdx.x, lane = tid & 63, w = tid >> 6;
  const int wm = w & 1, wn = w >> 1;
  const int quad = lane >> 4, l15 = lane & 15;

  // staging map: lane l covers byte l*16 of a 16-row x 64B panel
  // srow = w*32 + lane/4, col = (lane&3)*8 u16  -> linear in LDS, gl16-compatible
  const int srow0 = w * 32 + (lane >> 2);
  const int srow1 = srow0 + 16;
  const int kch = (lane & 3) * 8;
  const int ar = lane >> 3, ac = lane & 7;

  const u16 *pa0 = nullptr, *pa1 = nullptr, *pg0 = nullptr, *pg1 = nullptr,
            *pu0 = nullptr, *pu1 = nullptr;
  const float *fa[4], *fg[4], *fu[4];
  int frow[4];

  if (SRC == 0) {
    int gi0 = c0 + m0 + srow0, gi1 = c0 + m0 + srow1;
    int tok0 = (gi0 < cnt) ? (list ? list[gi0] : gi0) : 0;
    int tok1 = (gi1 < cnt) ? (list ? list[gi1] : gi1) : 0;
    pa0 = xb + (size_t)tok0 * HDIM + kch;
    pa1 = xb + (size_t)tok1 * HDIM + kch;
    pg0 = Wg_b + (size_t)(n0 + srow0) * HDIM + kch;
    pg1 = Wg_b + (size_t)(n0 + srow1) * HDIM + kch;
    pu0 = Wu_b + (size_t)(n0 + srow0) * HDIM + kch;
    pu1 = Wu_b + (size_t)(n0 + srow1) * HDIM + kch;
  } else {
    #pragma unroll
    for (int p = 0; p < 4; ++p) {
      int row = w * 32 + p * 8 + ar;
      frow[p] = row;
      int gi = c0 + m0 + row;
      int tok = (gi < cnt) ? (list ? list[gi] : gi) : 0;
      fa[p] = xf + (size_t)tok * HDIM + ac * 4;
      fg[p] = Wg_f + (size_t)(n0 + row) * HDIM + ac * 4;
      fu[p] = Wu_f + (size_t)(n0 + row) * HDIM + ac * 4;
    }
  }

  const u16* fA = sA + (wm * 64 + l15) * 32 + quad * 8;
  const u16* fG = sG + (wn * 64 + l15) * 32 + quad * 8;
  const u16* fU = sU + (wn * 64 + l15) * 32 + quad * 8;

  f32x4 accG[4][4] = {};
  f32x4 accU[4][4] = {};

  for (int kt = 0; kt < HDIM / 32; ++kt) {
    if (SRC == 0) {
      // async global->LDS: wave w owns rows [w*32, w*32+32) of each tile
      gl16(pa0 + kt * 32, sA + w * 1024);
      gl16(pa1 + kt * 32, sA + w * 1024 + 512);
      gl16(pg0 + kt * 32, sG + w * 1024);
      gl16(pg1 + kt * 32, sG + w * 1024 + 512);
      gl16(pu0 + kt * 32, sU + w * 1024);
      gl16(pu1 + kt * 32, sU + w * 1024 + 512);
    } else {
      #pragma unroll
      for (int p = 0; p < 4; ++p) {
        f32x4 va = *(const f32x4*)(fa[p] + kt * 32);
        f32x4 vg = *(const f32x4*)(fg[p] + kt * 32);
        f32x4 vu = *(const f32x4*)(fu[p] + kt * 32);
        uint2 oa; oa.x = pack2(va[0], va[1]); oa.y = pack2(va[2], va[3]);
        uint2 og; og.x = pack2(vg[0], vg[1]); og.y = pack2(vg[2], vg[3]);
        uint2 ou; ou.x = pack2(vu[0], vu[1]); ou.y = pack2(vu[2], vu[3]);
        *(uint2*)(sA + frow[p] * 32 + ac * 4) = oa;
        *(uint2*)(sG + frow[p] * 32 + ac * 4) = og;
        *(uint2*)(sU + frow[p] * 32 + ac * 4) = ou;
      }
    }
    __syncthreads();
    bf16x8 a[4];
    #pragma unroll
    for (int mt = 0; mt < 4; ++mt) a[mt] = *(const bf16x8*)(fA + mt * 16 * 32);
    #pragma unroll
    for (int nt = 0; nt < 4; ++nt) {
      bf16x8 bg = *(const bf16x8*)(fG + nt * 16 * 32);
      bf16x8 bu = *(const bf16x8*)(fU + nt * 16 * 32);
      #pragma unroll
      for (int mt = 0; mt < 4; ++mt) {
        accG[mt][nt] = __builtin_amdgcn_mfma_f32_16x16x32_bf16(a[mt], bg, accG[mt][nt], 0, 0, 0);
        accU[mt][nt] = __builtin_amdgcn_mfma_f32_16x16x32_bf16(a[mt], bu, accU[mt][nt], 0, 0, 0);
      }
    }
    __syncthreads();
  }

  #pragma unroll
  for (int mt = 0; mt < 4; ++mt) {
    #pragma unroll
    for (int i = 0; i < 4; ++i) {
      int row = m0 + wm * 64 + mt * 16 + quad * 4 + i;
      if (row < remain) {
        u16* orow = hbuf + (size_t)row * IDIM + n0 + wn * 64 + l15;
        #pragma unroll
        for (int nt = 0; nt < 4; ++nt) {
          float g = accG[mt][nt][i], u = accU[mt][nt][i];
          float h = (g / (1.f + __expf(-g))) * u;
          orow[nt * 16] = f2bf(h);
        }
      }
    }
  }
}

// ---------------- pass B: out[tok] (+)= cw * (h Wd^T)  (f32 output!) --------
template<int SRC>
__global__ __launch_bounds__(256, 2) void moe_down_k(
    const u16* __restrict__ hbuf,
    const u16* __restrict__ Wd_b, const float* __restrict__ Wd_f,
    const int* __restrict__ list, const int* __restrict__ count_ptr,
    const float* __restrict__ cw, int expert, float* __restrict__ out, int c0)
{
  __shared__ __align__(16) u16 sA[128 * 32];
  __shared__ __align__(16) u16 sB[128 * 32];

  const int cnt = count_ptr ? *count_ptr : T_TOK;
  const int remain = cnt - c0;
  const int m0 = blockIdx.y * 128;
  if (m0 >= remain) return;
  const int n0 = blockIdx.x * 128;

  const int tid = threadIdx.x, lane = tid & 63, w = tid >> 6;
  const int wm = w & 1, wn = w >> 1;
  const int quad = lane >> 4, l15 = lane & 15;

  const int srow0 = w * 32 + (lane >> 2);
  const int srow1 = srow0 + 16;
  const int kch = (lane & 3) * 8;
  const int ar = lane >> 3, ac = lane & 7;

  const u16* pa0 = hbuf + (size_t)(m0 + srow0) * IDIM + kch;
  const u16* pa1 = hbuf + (size_t)(m0 + srow1) * IDIM + kch;
  const u16 *pb0 = nullptr, *pb1 = nullptr;
  const float* fb[4];
  int frow[4];
  if (SRC == 0) {
    pb0 = Wd_b + (size_t)(n0 + srow0) * IDIM + kch;
    pb1 = Wd_b + (size_t)(n0 + srow1) * IDIM + kch;
  } else {
    #pragma unroll
    for (int p = 0; p < 4; ++p) {
      int row = w * 32 + p * 8 + ar;
      frow[p] = row;
      fb[p] = Wd_f + (size_t)(n0 + row) * IDIM + ac * 4;
    }
  }

  const u16* fA = sA + (wm * 64 + l15) * 32 + quad * 8;
  const u16* fB = sB + (wn * 64 + l15) * 32 + quad * 8;

  f32x4 acc[4][4] = {};

  for (int kt = 0; kt < IDIM / 32; ++kt) {
    // A tile (hbuf is always bf16): async global->LDS
    gl16(pa0 + kt * 32, sA + w * 1024);
    gl16(pa1 + kt * 32, sA + w * 1024 + 512);
    if (SRC == 0) {
      gl16(pb0 + kt * 32, sB + w * 1024);
      gl16(pb1 + kt * 32, sB + w * 1024 + 512);
    } else {
      #pragma unroll
      for (int p = 0; p < 4; ++p) {
        f32x4 v = *(const f32x4*)(fb[p] + kt * 32);
        uint2 o; o.x = pack2(v[0], v[1]); o.y = pack2(v[2], v[3]);
        *(uint2*)(sB + frow[p] * 32 + ac * 4) = o;
      }
    }
    __syncthreads();
    bf16x8 a[4];
    #pragma unroll
    for (int mt = 0; mt < 4; ++mt) a[mt] = *(const bf16x8*)(fA + mt * 16 * 32);
    #pragma unroll
    for (int nt = 0; nt < 4; ++nt) {
      bf16x8 b = *(const bf16x8*)(fB + nt * 16 * 32);
      #pragma unroll
      for (int mt = 0; mt < 4; ++mt)
        acc[mt][nt] = __builtin_amdgcn_mfma_f32_16x16x32_bf16(a[mt], b, acc[mt][nt], 0, 0, 0);
    }
    __syncthreads();
  }

  #pragma unroll
  for (int mt = 0; mt < 4; ++mt) {
    #pragma unroll
    for (int i = 0; i < 4; ++i) {
      int rl = m0 + wm * 64 + mt * 16 + quad * 4 + i;
      if (rl < remain) {
        int token = list ? list[c0 + rl] : (c0 + rl);
        float s = (expert >= 0) ? cw[(size_t)token * NEXP + expert] : 1.f;
        float* orow = out + (size_t)token * HDIM + n0 + wn * 64 + l15;
        #pragma unroll
        for (int nt = 0; nt < 4; ++nt) {
          float v = s * acc[mt][nt][i];
          if (expert >= 0) v += orow[nt * 16];
          orow[nt * 16] = v;
        }
      }
    }
  }
}

extern "C" void kernel_launch(void* const* d_in, const int* in_sizes, int n_in,
                              void* d_out, int out_size, void* d_ws, size_t ws_size,
                              hipStream_t stream) {
  (void)in_sizes; (void)n_in; (void)out_size;
  const float* x    = (const float*)d_in[0];
  const float* Wg_s = (const float*)d_in[1];
  const float* Wu_s = (const float*)d_in[2];
  const float* Wd_s = (const float*)d_in[3];
  const float* Wg   = (const float*)d_in[4];
  const float* Wu   = (const float*)d_in[5];
  const float* Wd   = (const float*)d_in[6];
  const float* Wr   = (const float*)d_in[7];
  const float* rb   = (const float*)d_in[8];
  float* out = (float*)d_out;

  char* ws = (char*)d_ws;
  size_t off = 1024;               // counts: NEXP * CNT_STRIDE ints = 1 KB
  int* counts = (int*)ws;
  int* lists = (int*)(ws + off);  off += (size_t)NEXP * T_TOK * 4;
  float* cw = (float*)(ws + off); off += (size_t)T_TOK * NEXP * 4;

  const size_t WSH = (size_t)IDIM * HDIM;
  const size_t xc_elems = (size_t)T_TOK * HDIM;
  const size_t wc_elems = 3 * WSH + 3 * NEXP * WSH;   // 27*WSH
  const size_t fast_need = off + (xc_elems + wc_elems) * 2 + (size_t)2048 * IDIM * 2;
  const bool fast = ws_size >= fast_need;

  u16* xc = (u16*)(ws + off);
  u16* wgs_c = xc + (fast ? xc_elems : 0);
  u16* wus_c = wgs_c + WSH;
  u16* wds_c = wus_c + WSH;
  u16* wg_c = wds_c + WSH;
  u16* wu_c = wg_c + NEXP * WSH;
  u16* wd_c = wu_c + NEXP * WSH;

  size_t hoff = off + (fast ? (xc_elems + wc_elems) * 2 : 0);
  u16* hbuf = (u16*)(ws + hoff);

  size_t avail = (ws_size > hoff) ? (ws_size - hoff) : 0;
  long long capll = (long long)(avail / ((size_t)IDIM * 2));
  int cap = (capll > T_TOK) ? T_TOK : (int)capll;
  cap &= ~127;
  if (cap < 128) cap = 128;
  int nchunks = (T_TOK + cap - 1) / cap;

  init_counts<<<1, NEXP * CNT_STRIDE, 0, stream>>>(counts);
  if (fast) {
    auto cv = [&](const float* s, u16* d, size_t n) {
      int blocks = (int)((n / 4 + 255) / 256);
      cvt_kernel<<<blocks, 256, 0, stream>>>(s, d, (int)n);
    };
    cv(x, xc, xc_elems);
    cv(Wg_s, wgs_c, WSH); cv(Wu_s, wus_c, WSH); cv(Wd_s, wds_c, WSH);
    cv(Wg, wg_c, NEXP * WSH); cv(Wu, wu_c, NEXP * WSH); cv(Wd, wd_c, NEXP * WSH);
  }
  router_kernel<<<T_TOK / TOK_PER_BLK, 256, 0, stream>>>(x, Wr, rb, cw, counts, lists);

  dim3 blk(256);
  dim3 gA(IDIM / 128, cap / 128);
  dim3 gB(HDIM / 128, cap / 128);

  // shared expert: overwrite-store covers every output element
  for (int c = 0; c < nchunks; ++c) {
    int c0 = c * cap;
    if (fast) {
      moe_gateup_k<0><<<gA, blk, 0, stream>>>(xc, nullptr, wgs_c, wus_c, nullptr, nullptr,
                                              nullptr, nullptr, hbuf, c0);
      moe_down_k<0><<<gB, blk, 0, stream>>>(hbuf, wds_c, nullptr, nullptr, nullptr,
                                            cw, -1, out, c0);
    } else {
      moe_gateup_k<1><<<gA, blk, 0, stream>>>(nullptr, x, nullptr, nullptr, Wg_s, Wu_s,
                                              nullptr, nullptr, hbuf, c0);
      moe_down_k<1><<<gB, blk, 0, stream>>>(hbuf, nullptr, Wd_s, nullptr, nullptr,
                                            cw, -1, out, c0);
    }
  }
  // routed experts: serialized read-modify-write accumulate (f32, no rounding)
  for (int e = 0; e < NEXP; ++e) {
    const int* lst = lists + (size_t)e * T_TOK;
    const int* cptr = counts + (size_t)e * CNT_STRIDE;
    for (int c = 0; c < nchunks; ++c) {
      int c0 = c * cap;
      if (fast) {
        moe_gateup_k<0><<<gA, blk, 0, stream>>>(xc, nullptr, wg_c + (size_t)e * WSH,
                                                wu_c + (size_t)e * WSH, nullptr, nullptr,
                                                lst, cptr, hbuf, c0);
        moe_down_k<0><<<gB, blk, 0, stream>>>(hbuf, wd_c + (size_t)e * WSH, nullptr,
                                              lst, cptr, cw, e, out, c0);
      } else {
        moe_gateup_k<1><<<gA, blk, 0, stream>>>(nullptr, x, nullptr, nullptr,
                                                Wg + (size_t)e * WSH, Wu + (size_t)e * WSH,
                                                lst, cptr, hbuf, c0);
        moe_down_k<1><<<gB, blk, 0, stream>>>(hbuf, nullptr, Wd + (size_t)e * WSH,
                                              lst, cptr, cw, e, out, c0);
      }
    }
  }
}

// Round 3
// 1271.524 us; speedup vs baseline: 1.3436x; 1.3436x over previous
//
#include <hip/hip_runtime.h>

#define T_TOK 16384
#define HDIM  1024
#define IDIM  2048
#define NEXP  8
#define CNT_STRIDE 32     // pad each expert counter to its own 128B cache line
#define TOK_PER_BLK 32    // tokens handled per 256-thread router block
#define MAX_RTILES 264    // max padded 128-row tiles over all routed experts

typedef __attribute__((ext_vector_type(8))) short bf16x8;
typedef __attribute__((ext_vector_type(4))) float f32x4;
typedef unsigned short u16;
typedef unsigned int u32;

typedef __attribute__((address_space(1))) const unsigned int gas_u32;
typedef __attribute__((address_space(3))) unsigned int las_u32;

// async global->LDS, 16B per lane; LDS dest = base + lane*16 (wave-uniform base)
__device__ __forceinline__ void gl16(const void* g, void* l) {
  __builtin_amdgcn_global_load_lds((gas_u32*)g, (las_u32*)l, 16, 0, 0);
}

__device__ __forceinline__ u16 f2bf(float f) {
  union { float f; u32 i; } v; v.f = f;
  u32 r = v.i + 0x7FFF + ((v.i >> 16) & 1);  // RNE
  return (u16)(r >> 16);
}
__device__ __forceinline__ u32 pack2(float a, float b) {
  return (u32)f2bf(a) | ((u32)f2bf(b) << 16);
}

// ---------------- f32 -> bf16 elementwise convert ---------------------------
__global__ __launch_bounds__(256) void cvt_kernel(
    const float* __restrict__ s, u16* __restrict__ d, int n)
{
  int i = (blockIdx.x * 256 + threadIdx.x) * 4;
  if (i < n) {
    f32x4 v = *(const f32x4*)(s + i);
    uint2 o; o.x = pack2(v[0], v[1]); o.y = pack2(v[2], v[3]);
    *(uint2*)(d + i) = o;
  }
}

__global__ void init_counts(int* counts) {
  counts[threadIdx.x] = 0;  // launched with NEXP*CNT_STRIDE threads
}

// ---------------- router: f64 logits, top2 on logits ------------------------
__global__ __launch_bounds__(256) void router_kernel(
    const float* __restrict__ x, const float* __restrict__ Wr,
    const float* __restrict__ rb, float* __restrict__ cw,
    int* __restrict__ counts, int* __restrict__ lists)
{
  __shared__ __align__(16) float sWr[NEXP * HDIM];   // 32 KB
  __shared__ int pickE[2 * TOK_PER_BLK];             // 64 slots
  __shared__ int pickT[2 * TOK_PER_BLK];

  const int tid = threadIdx.x;
  const int lane = tid & 63;
  const int wv = tid >> 6;

  for (int i = tid; i < NEXP * HDIM / 4; i += 256)
    ((f32x4*)sWr)[i] = ((const f32x4*)Wr)[i];

  float rbl[NEXP];
  #pragma unroll
  for (int e = 0; e < NEXP; ++e) rbl[e] = rb[e];

  __syncthreads();

  const int t_base = blockIdx.x * TOK_PER_BLK + wv * (TOK_PER_BLK / 4);
  for (int j = 0; j < TOK_PER_BLK / 4; ++j) {
    const int t = t_base + j;
    const float* xrow = x + (size_t)t * HDIM;
    f32x4 xv[4];
    #pragma unroll
    for (int c = 0; c < 4; ++c) xv[c] = *(const f32x4*)(xrow + c * 256 + lane * 4);

    double acc[NEXP];
    #pragma unroll
    for (int e = 0; e < NEXP; ++e) {
      const float* wr = sWr + e * HDIM;
      double a = 0.0;
      #pragma unroll
      for (int c = 0; c < 4; ++c) {
        f32x4 w4 = *(const f32x4*)(wr + c * 256 + lane * 4);
        a += (double)xv[c][0] * (double)w4[0];
        a += (double)xv[c][1] * (double)w4[1];
        a += (double)xv[c][2] * (double)w4[2];
        a += (double)xv[c][3] * (double)w4[3];
      }
      acc[e] = a;
    }
    #pragma unroll
    for (int e = 0; e < NEXP; ++e) {
      double a = acc[e];
      a += __shfl_xor(a, 1, 64);
      a += __shfl_xor(a, 2, 64);
      a += __shfl_xor(a, 4, 64);
      acc[e] = a;
    }
    double s0 = (lane & 1) ? acc[1] : acc[0];
    double s1 = (lane & 1) ? acc[3] : acc[2];
    double s2 = (lane & 1) ? acc[5] : acc[4];
    double s3 = (lane & 1) ? acc[7] : acc[6];
    double u0 = (lane & 2) ? s1 : s0;
    double u1 = (lane & 2) ? s3 : s2;
    double v  = (lane & 4) ? u1 : u0;
    v += __shfl_xor(v, 8, 64);
    v += __shfl_xor(v, 16, 64);
    v += __shfl_xor(v, 32, 64);
    double l[NEXP];
    #pragma unroll
    for (int e = 0; e < NEXP; ++e) l[e] = __shfl(v, e, 64) + (double)rbl[e];

    if (lane == 0) {
      int i1 = 0;
      #pragma unroll
      for (int e = 1; e < NEXP; ++e) if (l[e] > l[i1]) i1 = e;
      int i2 = -1;
      #pragma unroll
      for (int e = 0; e < NEXP; ++e) {
        if (e == i1) continue;
        if (i2 < 0 || l[e] > l[i2]) i2 = e;
      }
      float p1 = (float)(1.0 / (1.0 + exp(-l[i1])));
      float p2 = (float)(1.0 / (1.0 + exp(-l[i2])));
      cw[(size_t)t * NEXP + i1] = p1;
      cw[(size_t)t * NEXP + i2] = p2;
      int slot = (wv * (TOK_PER_BLK / 4) + j) * 2;
      pickE[slot] = i1; pickE[slot + 1] = i2;
      pickT[slot] = t;  pickT[slot + 1] = t;
    }
  }
  __syncthreads();

  const int myE = pickE[lane];
  const int myT = pickT[lane];
  #pragma unroll
  for (int ei = 0; ei < 2; ++ei) {
    int e = wv + ei * 4;
    unsigned long long b = __ballot(myE == e);
    int cnt = __popcll(b);
    int base = 0;
    if (lane == 0) base = atomicAdd(&counts[e * CNT_STRIDE], cnt);
    base = __shfl(base, 0, 64);
    if (myE == e)
      lists[(size_t)e * T_TOK + base + __popcll(b & ((1ull << lane) - 1))] = myT;
  }
}

// ---------------- build 128-row tile descriptors over all routed experts ----
__global__ void build_tiles(const int* __restrict__ counts,
                            int* __restrict__ td_e, int* __restrict__ td_r0,
                            int* __restrict__ ntiles)
{
  if (threadIdx.x == 0) {
    int n = 0;
    for (int e = 0; e < NEXP; ++e) {
      int c = counts[e * CNT_STRIDE];
      for (int r = 0; r < c; r += 128) { td_e[n] = e; td_r0[n] = r; ++n; }
    }
    *ntiles = n;
  }
}

// ---------------- shared-expert pass A (dense, bf16/f32 variants) -----------
template<int SRC>
__global__ __launch_bounds__(256, 2) void moe_gateup_k(
    const u16* __restrict__ xb, const float* __restrict__ xf,
    const u16* __restrict__ Wg_b, const u16* __restrict__ Wu_b,
    const float* __restrict__ Wg_f, const float* __restrict__ Wu_f,
    const int* __restrict__ list, const int* __restrict__ count_ptr,
    u16* __restrict__ hbuf, int c0)
{
  __shared__ __align__(16) u16 sA[128 * 32];
  __shared__ __align__(16) u16 sG[128 * 32];
  __shared__ __align__(16) u16 sU[128 * 32];

  const int cnt = count_ptr ? *count_ptr : T_TOK;
  const int remain = cnt - c0;
  const int m0 = blockIdx.y * 128;
  if (m0 >= remain) return;
  const int n0 = blockIdx.x * 128;

  const int tid = threadIdx.x, lane = tid & 63, w = tid >> 6;
  const int wm = w & 1, wn = w >> 1;
  const int quad = lane >> 4, l15 = lane & 15;

  const int srow0 = w * 32 + (lane >> 2);
  const int srow1 = srow0 + 16;
  const int kch = (lane & 3) * 8;
  const int ar = lane >> 3, ac = lane & 7;

  const u16 *pa0 = nullptr, *pa1 = nullptr, *pg0 = nullptr, *pg1 = nullptr,
            *pu0 = nullptr, *pu1 = nullptr;
  const float *fa[4], *fg[4], *fu[4];
  int frow[4];

  if (SRC == 0) {
    int gi0 = c0 + m0 + srow0, gi1 = c0 + m0 + srow1;
    int tok0 = (gi0 < cnt) ? (list ? list[gi0] : gi0) : 0;
    int tok1 = (gi1 < cnt) ? (list ? list[gi1] : gi1) : 0;
    pa0 = xb + (size_t)tok0 * HDIM + kch;
    pa1 = xb + (size_t)tok1 * HDIM + kch;
    pg0 = Wg_b + (size_t)(n0 + srow0) * HDIM + kch;
    pg1 = Wg_b + (size_t)(n0 + srow1) * HDIM + kch;
    pu0 = Wu_b + (size_t)(n0 + srow0) * HDIM + kch;
    pu1 = Wu_b + (size_t)(n0 + srow1) * HDIM + kch;
  } else {
    #pragma unroll
    for (int p = 0; p < 4; ++p) {
      int row = w * 32 + p * 8 + ar;
      frow[p] = row;
      int gi = c0 + m0 + row;
      int tok = (gi < cnt) ? (list ? list[gi] : gi) : 0;
      fa[p] = xf + (size_t)tok * HDIM + ac * 4;
      fg[p] = Wg_f + (size_t)(n0 + row) * HDIM + ac * 4;
      fu[p] = Wu_f + (size_t)(n0 + row) * HDIM + ac * 4;
    }
  }

  const u16* fA = sA + (wm * 64 + l15) * 32 + quad * 8;
  const u16* fG = sG + (wn * 64 + l15) * 32 + quad * 8;
  const u16* fU = sU + (wn * 64 + l15) * 32 + quad * 8;

  f32x4 accG[4][4] = {};
  f32x4 accU[4][4] = {};

  for (int kt = 0; kt < HDIM / 32; ++kt) {
    if (SRC == 0) {
      gl16(pa0 + kt * 32, sA + w * 1024);
      gl16(pa1 + kt * 32, sA + w * 1024 + 512);
      gl16(pg0 + kt * 32, sG + w * 1024);
      gl16(pg1 + kt * 32, sG + w * 1024 + 512);
      gl16(pu0 + kt * 32, sU + w * 1024);
      gl16(pu1 + kt * 32, sU + w * 1024 + 512);
    } else {
      #pragma unroll
      for (int p = 0; p < 4; ++p) {
        f32x4 va = *(const f32x4*)(fa[p] + kt * 32);
        f32x4 vg = *(const f32x4*)(fg[p] + kt * 32);
        f32x4 vu = *(const f32x4*)(fu[p] + kt * 32);
        uint2 oa; oa.x = pack2(va[0], va[1]); oa.y = pack2(va[2], va[3]);
        uint2 og; og.x = pack2(vg[0], vg[1]); og.y = pack2(vg[2], vg[3]);
        uint2 ou; ou.x = pack2(vu[0], vu[1]); ou.y = pack2(vu[2], vu[3]);
        *(uint2*)(sA + frow[p] * 32 + ac * 4) = oa;
        *(uint2*)(sG + frow[p] * 32 + ac * 4) = og;
        *(uint2*)(sU + frow[p] * 32 + ac * 4) = ou;
      }
    }
    __syncthreads();
    bf16x8 a[4];
    #pragma unroll
    for (int mt = 0; mt < 4; ++mt) a[mt] = *(const bf16x8*)(fA + mt * 16 * 32);
    #pragma unroll
    for (int nt = 0; nt < 4; ++nt) {
      bf16x8 bg = *(const bf16x8*)(fG + nt * 16 * 32);
      bf16x8 bu = *(const bf16x8*)(fU + nt * 16 * 32);
      #pragma unroll
      for (int mt = 0; mt < 4; ++mt) {
        accG[mt][nt] = __builtin_amdgcn_mfma_f32_16x16x32_bf16(a[mt], bg, accG[mt][nt], 0, 0, 0);
        accU[mt][nt] = __builtin_amdgcn_mfma_f32_16x16x32_bf16(a[mt], bu, accU[mt][nt], 0, 0, 0);
      }
    }
    __syncthreads();
  }

  #pragma unroll
  for (int mt = 0; mt < 4; ++mt) {
    #pragma unroll
    for (int i = 0; i < 4; ++i) {
      int row = m0 + wm * 64 + mt * 16 + quad * 4 + i;
      if (row < remain) {
        u16* orow = hbuf + (size_t)row * IDIM + n0 + wn * 64 + l15;
        #pragma unroll
        for (int nt = 0; nt < 4; ++nt) {
          float g = accG[mt][nt][i], u = accU[mt][nt][i];
          float h = (g / (1.f + __expf(-g))) * u;
          orow[nt * 16] = f2bf(h);
        }
      }
    }
  }
}

// ---------------- shared-expert pass B (dense) ------------------------------
template<int SRC>
__global__ __launch_bounds__(256, 2) void moe_down_k(
    const u16* __restrict__ hbuf,
    const u16* __restrict__ Wd_b, const float* __restrict__ Wd_f,
    const int* __restrict__ list, const int* __restrict__ count_ptr,
    const float* __restrict__ cw, int expert, float* __restrict__ out, int c0)
{
  __shared__ __align__(16) u16 sA[128 * 32];
  __shared__ __align__(16) u16 sB[128 * 32];

  const int cnt = count_ptr ? *count_ptr : T_TOK;
  const int remain = cnt - c0;
  const int m0 = blockIdx.y * 128;
  if (m0 >= remain) return;
  const int n0 = blockIdx.x * 128;

  const int tid = threadIdx.x, lane = tid & 63, w = tid >> 6;
  const int wm = w & 1, wn = w >> 1;
  const int quad = lane >> 4, l15 = lane & 15;

  const int srow0 = w * 32 + (lane >> 2);
  const int srow1 = srow0 + 16;
  const int kch = (lane & 3) * 8;
  const int ar = lane >> 3, ac = lane & 7;

  const u16* pa0 = hbuf + (size_t)(m0 + srow0) * IDIM + kch;
  const u16* pa1 = hbuf + (size_t)(m0 + srow1) * IDIM + kch;
  const u16 *pb0 = nullptr, *pb1 = nullptr;
  const float* fb[4];
  int frow[4];
  if (SRC == 0) {
    pb0 = Wd_b + (size_t)(n0 + srow0) * IDIM + kch;
    pb1 = Wd_b + (size_t)(n0 + srow1) * IDIM + kch;
  } else {
    #pragma unroll
    for (int p = 0; p < 4; ++p) {
      int row = w * 32 + p * 8 + ar;
      frow[p] = row;
      fb[p] = Wd_f + (size_t)(n0 + row) * IDIM + ac * 4;
    }
  }

  const u16* fA = sA + (wm * 64 + l15) * 32 + quad * 8;
  const u16* fB = sB + (wn * 64 + l15) * 32 + quad * 8;

  f32x4 acc[4][4] = {};

  for (int kt = 0; kt < IDIM / 32; ++kt) {
    gl16(pa0 + kt * 32, sA + w * 1024);
    gl16(pa1 + kt * 32, sA + w * 1024 + 512);
    if (SRC == 0) {
      gl16(pb0 + kt * 32, sB + w * 1024);
      gl16(pb1 + kt * 32, sB + w * 1024 + 512);
    } else {
      #pragma unroll
      for (int p = 0; p < 4; ++p) {
        f32x4 v = *(const f32x4*)(fb[p] + kt * 32);
        uint2 o; o.x = pack2(v[0], v[1]); o.y = pack2(v[2], v[3]);
        *(uint2*)(sB + frow[p] * 32 + ac * 4) = o;
      }
    }
    __syncthreads();
    bf16x8 a[4];
    #pragma unroll
    for (int mt = 0; mt < 4; ++mt) a[mt] = *(const bf16x8*)(fA + mt * 16 * 32);
    #pragma unroll
    for (int nt = 0; nt < 4; ++nt) {
      bf16x8 b = *(const bf16x8*)(fB + nt * 16 * 32);
      #pragma unroll
      for (int mt = 0; mt < 4; ++mt)
        acc[mt][nt] = __builtin_amdgcn_mfma_f32_16x16x32_bf16(a[mt], b, acc[mt][nt], 0, 0, 0);
    }
    __syncthreads();
  }

  #pragma unroll
  for (int mt = 0; mt < 4; ++mt) {
    #pragma unroll
    for (int i = 0; i < 4; ++i) {
      int rl = m0 + wm * 64 + mt * 16 + quad * 4 + i;
      if (rl < remain) {
        int token = list ? list[c0 + rl] : (c0 + rl);
        float s = (expert >= 0) ? cw[(size_t)token * NEXP + expert] : 1.f;
        float* orow = out + (size_t)token * HDIM + n0 + wn * 64 + l15;
        #pragma unroll
        for (int nt = 0; nt < 4; ++nt) {
          float v = s * acc[mt][nt][i];
          if (expert >= 0) v += orow[nt * 16];
          orow[nt * 16] = v;
        }
      }
    }
  }
}

// ---------------- FUSED routed pass A: all experts in one dispatch ----------
__global__ __launch_bounds__(256, 2) void moe_gateup_fused(
    const u16* __restrict__ xb,
    const u16* __restrict__ Wg_b, const u16* __restrict__ Wu_b,
    const int* __restrict__ lists, const int* __restrict__ counts,
    const int* __restrict__ td_e, const int* __restrict__ td_r0,
    const int* __restrict__ ntiles,
    u16* __restrict__ hbuf, int t0)
{
  __shared__ __align__(16) u16 sA[128 * 32];
  __shared__ __align__(16) u16 sG[128 * 32];
  __shared__ __align__(16) u16 sU[128 * 32];

  const int ty = t0 + blockIdx.y;
  if (ty >= *ntiles) return;
  const int e = td_e[ty];
  const int r0 = td_r0[ty];
  const int cnt = counts[e * CNT_STRIDE];
  const int* list = lists + (size_t)e * T_TOK;
  const size_t WSH = (size_t)IDIM * HDIM;
  const u16* Wg_e = Wg_b + (size_t)e * WSH;
  const u16* Wu_e = Wu_b + (size_t)e * WSH;
  const int n0 = blockIdx.x * 128;

  const int tid = threadIdx.x, lane = tid & 63, w = tid >> 6;
  const int wm = w & 1, wn = w >> 1;
  const int quad = lane >> 4, l15 = lane & 15;

  const int srow0 = w * 32 + (lane >> 2);
  const int srow1 = srow0 + 16;
  const int kch = (lane & 3) * 8;

  int gi0 = r0 + srow0, gi1 = r0 + srow1;
  int tok0 = (gi0 < cnt) ? list[gi0] : 0;
  int tok1 = (gi1 < cnt) ? list[gi1] : 0;
  const u16* pa0 = xb + (size_t)tok0 * HDIM + kch;
  const u16* pa1 = xb + (size_t)tok1 * HDIM + kch;
  const u16* pg0 = Wg_e + (size_t)(n0 + srow0) * HDIM + kch;
  const u16* pg1 = Wg_e + (size_t)(n0 + srow1) * HDIM + kch;
  const u16* pu0 = Wu_e + (size_t)(n0 + srow0) * HDIM + kch;
  const u16* pu1 = Wu_e + (size_t)(n0 + srow1) * HDIM + kch;

  const u16* fA = sA + (wm * 64 + l15) * 32 + quad * 8;
  const u16* fG = sG + (wn * 64 + l15) * 32 + quad * 8;
  const u16* fU = sU + (wn * 64 + l15) * 32 + quad * 8;

  f32x4 accG[4][4] = {};
  f32x4 accU[4][4] = {};

  for (int kt = 0; kt < HDIM / 32; ++kt) {
    gl16(pa0 + kt * 32, sA + w * 1024);
    gl16(pa1 + kt * 32, sA + w * 1024 + 512);
    gl16(pg0 + kt * 32, sG + w * 1024);
    gl16(pg1 + kt * 32, sG + w * 1024 + 512);
    gl16(pu0 + kt * 32, sU + w * 1024);
    gl16(pu1 + kt * 32, sU + w * 1024 + 512);
    __syncthreads();
    bf16x8 a[4];
    #pragma unroll
    for (int mt = 0; mt < 4; ++mt) a[mt] = *(const bf16x8*)(fA + mt * 16 * 32);
    #pragma unroll
    for (int nt = 0; nt < 4; ++nt) {
      bf16x8 bg = *(const bf16x8*)(fG + nt * 16 * 32);
      bf16x8 bu = *(const bf16x8*)(fU + nt * 16 * 32);
      #pragma unroll
      for (int mt = 0; mt < 4; ++mt) {
        accG[mt][nt] = __builtin_amdgcn_mfma_f32_16x16x32_bf16(a[mt], bg, accG[mt][nt], 0, 0, 0);
        accU[mt][nt] = __builtin_amdgcn_mfma_f32_16x16x32_bf16(a[mt], bu, accU[mt][nt], 0, 0, 0);
      }
    }
    __syncthreads();
  }

  // hbuf rows are chunk-local: blockIdx.y*128 + local row (pad rows hold junk)
  #pragma unroll
  for (int mt = 0; mt < 4; ++mt) {
    #pragma unroll
    for (int i = 0; i < 4; ++i) {
      int rl = wm * 64 + mt * 16 + quad * 4 + i;
      u16* orow = hbuf + (size_t)(blockIdx.y * 128 + rl) * IDIM + n0 + wn * 64 + l15;
      #pragma unroll
      for (int nt = 0; nt < 4; ++nt) {
        float g = accG[mt][nt][i], u = accU[mt][nt][i];
        float h = (g / (1.f + __expf(-g))) * u;
        orow[nt * 16] = f2bf(h);
      }
    }
  }
}

// ---------------- FUSED routed pass B: atomic accumulate into out -----------
__global__ __launch_bounds__(256, 2) void moe_down_fused(
    const u16* __restrict__ hbuf, const u16* __restrict__ Wd_b,
    const int* __restrict__ lists, const int* __restrict__ counts,
    const int* __restrict__ td_e, const int* __restrict__ td_r0,
    const int* __restrict__ ntiles,
    const float* __restrict__ cw, float* __restrict__ out, int t0)
{
  __shared__ __align__(16) u16 sA[128 * 32];
  __shared__ __align__(16) u16 sB[128 * 32];

  const int ty = t0 + blockIdx.y;
  if (ty >= *ntiles) return;
  const int e = td_e[ty];
  const int r0 = td_r0[ty];
  const int cnt = counts[e * CNT_STRIDE];
  const int* list = lists + (size_t)e * T_TOK;
  const size_t WSH = (size_t)IDIM * HDIM;
  const u16* Wd_e = Wd_b + (size_t)e * WSH;
  const int n0 = blockIdx.x * 128;

  const int tid = threadIdx.x, lane = tid & 63, w = tid >> 6;
  const int wm = w & 1, wn = w >> 1;
  const int quad = lane >> 4, l15 = lane & 15;

  const int srow0 = w * 32 + (lane >> 2);
  const int srow1 = srow0 + 16;
  const int kch = (lane & 3) * 8;

  const u16* pa0 = hbuf + (size_t)(blockIdx.y * 128 + srow0) * IDIM + kch;
  const u16* pa1 = hbuf + (size_t)(blockIdx.y * 128 + srow1) * IDIM + kch;
  const u16* pb0 = Wd_e + (size_t)(n0 + srow0) * IDIM + kch;
  const u16* pb1 = Wd_e + (size_t)(n0 + srow1) * IDIM + kch;

  const u16* fA = sA + (wm * 64 + l15) * 32 + quad * 8;
  const u16* fB = sB + (wn * 64 + l15) * 32 + quad * 8;

  f32x4 acc[4][4] = {};

  for (int kt = 0; kt < IDIM / 32; ++kt) {
    gl16(pa0 + kt * 32, sA + w * 1024);
    gl16(pa1 + kt * 32, sA + w * 1024 + 512);
    gl16(pb0 + kt * 32, sB + w * 1024);
    gl16(pb1 + kt * 32, sB + w * 1024 + 512);
    __syncthreads();
    bf16x8 a[4];
    #pragma unroll
    for (int mt = 0; mt < 4; ++mt) a[mt] = *(const bf16x8*)(fA + mt * 16 * 32);
    #pragma unroll
    for (int nt = 0; nt < 4; ++nt) {
      bf16x8 b = *(const bf16x8*)(fB + nt * 16 * 32);
      #pragma unroll
      for (int mt = 0; mt < 4; ++mt)
        acc[mt][nt] = __builtin_amdgcn_mfma_f32_16x16x32_bf16(a[mt], b, acc[mt][nt], 0, 0, 0);
    }
    __syncthreads();
  }

  #pragma unroll
  for (int mt = 0; mt < 4; ++mt) {
    #pragma unroll
    for (int i = 0; i < 4; ++i) {
      int rl = wm * 64 + mt * 16 + quad * 4 + i;
      if (r0 + rl < cnt) {
        int token = list[r0 + rl];
        float s = cw[(size_t)token * NEXP + e];
        float* orow = out + (size_t)token * HDIM + n0 + wn * 64 + l15;
        #pragma unroll
        for (int nt = 0; nt < 4; ++nt)
          atomicAdd(&orow[nt * 16], s * acc[mt][nt][i]);
      }
    }
  }
}

extern "C" void kernel_launch(void* const* d_in, const int* in_sizes, int n_in,
                              void* d_out, int out_size, void* d_ws, size_t ws_size,
                              hipStream_t stream) {
  (void)in_sizes; (void)n_in; (void)out_size;
  const float* x    = (const float*)d_in[0];
  const float* Wg_s = (const float*)d_in[1];
  const float* Wu_s = (const float*)d_in[2];
  const float* Wd_s = (const float*)d_in[3];
  const float* Wg   = (const float*)d_in[4];
  const float* Wu   = (const float*)d_in[5];
  const float* Wd   = (const float*)d_in[6];
  const float* Wr   = (const float*)d_in[7];
  const float* rb   = (const float*)d_in[8];
  float* out = (float*)d_out;

  char* ws = (char*)d_ws;
  size_t off = 1024;               // counts: NEXP * CNT_STRIDE ints = 1 KB
  int* counts = (int*)ws;
  int* lists = (int*)(ws + off);  off += (size_t)NEXP * T_TOK * 4;
  float* cw = (float*)(ws + off); off += (size_t)T_TOK * NEXP * 4;
  int* td = (int*)(ws + off);     off += 2304;  // td_e | td_r0 | ntiles
  int* td_e = td;
  int* td_r0 = td + MAX_RTILES;
  int* ntiles = td + 2 * MAX_RTILES;

  const size_t WSH = (size_t)IDIM * HDIM;
  const size_t xc_elems = (size_t)T_TOK * HDIM;
  const size_t wc_elems = 3 * WSH + 3 * NEXP * WSH;   // 27*WSH
  const size_t fast_need = off + (xc_elems + wc_elems) * 2 + (size_t)2048 * IDIM * 2;
  const bool fast = ws_size >= fast_need;

  u16* xc = (u16*)(ws + off);
  u16* wgs_c = xc + (fast ? xc_elems : 0);
  u16* wus_c = wgs_c + WSH;
  u16* wds_c = wus_c + WSH;
  u16* wg_c = wds_c + WSH;
  u16* wu_c = wg_c + NEXP * WSH;
  u16* wd_c = wu_c + NEXP * WSH;

  size_t hoff = off + (fast ? (xc_elems + wc_elems) * 2 : 0);
  u16* hbuf = (u16*)(ws + hoff);

  size_t avail = (ws_size > hoff) ? (ws_size - hoff) : 0;
  long long capll = (long long)(avail / ((size_t)IDIM * 2));
  int cap = (capll > T_TOK) ? T_TOK : (int)capll;
  cap &= ~127;
  if (cap < 128) cap = 128;
  int nchunks = (T_TOK + cap - 1) / cap;

  init_counts<<<1, NEXP * CNT_STRIDE, 0, stream>>>(counts);
  if (fast) {
    auto cv = [&](const float* s, u16* d, size_t n) {
      int blocks = (int)((n / 4 + 255) / 256);
      cvt_kernel<<<blocks, 256, 0, stream>>>(s, d, (int)n);
    };
    cv(x, xc, xc_elems);
    cv(Wg_s, wgs_c, WSH); cv(Wu_s, wus_c, WSH); cv(Wd_s, wds_c, WSH);
    cv(Wg, wg_c, NEXP * WSH); cv(Wu, wu_c, NEXP * WSH); cv(Wd, wd_c, NEXP * WSH);
  }
  router_kernel<<<T_TOK / TOK_PER_BLK, 256, 0, stream>>>(x, Wr, rb, cw, counts, lists);

  dim3 blk(256);
  dim3 gA(IDIM / 128, cap / 128);
  dim3 gB(HDIM / 128, cap / 128);

  // shared expert: overwrite-store covers every output element
  for (int c = 0; c < nchunks; ++c) {
    int c0 = c * cap;
    if (fast) {
      moe_gateup_k<0><<<gA, blk, 0, stream>>>(xc, nullptr, wgs_c, wus_c, nullptr, nullptr,
                                              nullptr, nullptr, hbuf, c0);
      moe_down_k<0><<<gB, blk, 0, stream>>>(hbuf, wds_c, nullptr, nullptr, nullptr,
                                            cw, -1, out, c0);
    } else {
      moe_gateup_k<1><<<gA, blk, 0, stream>>>(nullptr, x, nullptr, nullptr, Wg_s, Wu_s,
                                              nullptr, nullptr, hbuf, c0);
      moe_down_k<1><<<gB, blk, 0, stream>>>(hbuf, nullptr, Wd_s, nullptr, nullptr,
                                            cw, -1, out, c0);
    }
  }

  if (fast) {
    // routed experts fused: tile descriptors over all experts, chunked by hbuf cap
    build_tiles<<<1, 64, 0, stream>>>(counts, td_e, td_r0, ntiles);
    int tpc = cap / 128;  // tiles per chunk
    for (int t0 = 0; t0 < MAX_RTILES; t0 += tpc) {
      int ytiles = (MAX_RTILES - t0 < tpc) ? (MAX_RTILES - t0) : tpc;
      dim3 gAf(IDIM / 128, ytiles);
      dim3 gBf(HDIM / 128, ytiles);
      moe_gateup_fused<<<gAf, blk, 0, stream>>>(xc, wg_c, wu_c, lists, counts,
                                                td_e, td_r0, ntiles, hbuf, t0);
      moe_down_fused<<<gBf, blk, 0, stream>>>(hbuf, wd_c, lists, counts,
                                              td_e, td_r0, ntiles, cw, out, t0);
    }
  } else {
    // fallback: per-expert serialized RMW accumulate (f32, no rounding change)
    for (int e = 0; e < NEXP; ++e) {
      const int* lst = lists + (size_t)e * T_TOK;
      const int* cptr = counts + (size_t)e * CNT_STRIDE;
      for (int c = 0; c < nchunks; ++c) {
        int c0 = c * cap;
        moe_gateup_k<1><<<gA, blk, 0, stream>>>(nullptr, x, nullptr, nullptr,
                                                Wg + (size_t)e * WSH, Wu + (size_t)e * WSH,
                                                lst, cptr, hbuf, c0);
        moe_down_k<1><<<gB, blk, 0, stream>>>(hbuf, nullptr, Wd + (size_t)e * WSH,
                                              lst, cptr, cw, e, out, c0);
      }
    }
  }
}